// Round 12
// baseline (232.534 us; speedup 1.0000x reference)
//
#include <hip/hip_runtime.h>

#define B_ 4
#define T_ 2048
#define C_ 1024
#define H_ 16
#define D_ 64
#define M_ (B_*T_)   // 8192 rows
#define CR3 3072     // fused QKV row stride

typedef unsigned short u16;
typedef __attribute__((ext_vector_type(8))) short short8;
typedef __attribute__((ext_vector_type(8))) unsigned short ushort8_t;
typedef __attribute__((ext_vector_type(4))) unsigned short ushort4_t;
typedef __attribute__((ext_vector_type(4))) float floatx4;
typedef __attribute__((ext_vector_type(16))) float f32x16;
typedef __attribute__((ext_vector_type(4))) unsigned int uint4_t;

__device__ __forceinline__ u16 f2bf(float f) {
  union { float f; unsigned u; } v; v.f = f;
  unsigned r = v.u + 0x7fffu + ((v.u >> 16) & 1u);
  return (u16)(r >> 16);
}

__device__ __forceinline__ void gload16(const void* g, void* l) {
  __builtin_amdgcn_global_load_lds((__attribute__((address_space(1))) void*)(g),
                                   (__attribute__((address_space(3))) void*)(l),
                                   16, 0, 0);
}

__device__ __forceinline__ unsigned cvtpk(float lo, float hi) {
  unsigned r;
  asm("v_cvt_pk_bf16_f32 %0, %1, %2" : "=v"(r) : "v"(lo), "v"(hi));
  return r;
}

__device__ __forceinline__ void pl32swap(unsigned &a, unsigned &b) {
  asm volatile("v_permlane32_swap_b32 %0, %1" : "+v"(a), "+v"(b));
}

#define MFMA32(a, b, c) __builtin_amdgcn_mfma_f32_32x32x16_bf16(a, b, c, 0, 0, 0)
#define MFMA16(a, b, c) __builtin_amdgcn_mfma_f32_16x16x32_bf16(a, b, c, 0, 0, 0)

// ---------------- x -> bf16 ----------------
__global__ __launch_bounds__(256) void convx_k(const float* __restrict__ x,
                                               u16* __restrict__ o) {
  int i = (blockIdx.x * 256 + threadIdx.x) * 4;
  floatx4 v = *(const floatx4*)(x + i);
  ushort4_t r;
#pragma unroll
  for (int j = 0; j < 4; ++j) r[j] = f2bf(v[j]);
  *(ushort4_t*)(o + i) = r;
}

// ------------- W (K x N) -> WT (N x K) bf16 (Wq pre-scaled), LDS transpose ----
__global__ __launch_bounds__(256) void wconv_k(const float* __restrict__ W0,
                                               const float* __restrict__ W1,
                                               const float* __restrict__ W2,
                                               const float* __restrict__ W3,
                                               u16* __restrict__ WT) {
  __shared__ float tile[64][65];
  const float* W = blockIdx.z == 0 ? W0 : blockIdx.z == 1 ? W1 : blockIdx.z == 2 ? W2 : W3;
  const float sc = blockIdx.z == 0 ? 0.125f * 1.44269504f : 1.0f;  // 1/sqrt(D)*log2e into Wq
  u16* Wt = WT + (size_t)blockIdx.z * (C_ * C_);
  int k0 = blockIdx.x * 64, n0 = blockIdx.y * 64;
  int t = threadIdx.x;
  int r = t >> 2, c0 = (t & 3) * 16;
#pragma unroll
  for (int j = 0; j < 4; ++j) {
    floatx4 v = *(const floatx4*)(W + (size_t)(k0 + r) * C_ + n0 + c0 + j * 4);
#pragma unroll
    for (int jj = 0; jj < 4; ++jj) tile[r][c0 + j * 4 + jj] = v[jj];
  }
  __syncthreads();
  ushort8_t o0, o1;
#pragma unroll
  for (int j = 0; j < 8; ++j) o0[j] = f2bf(tile[c0 + j][r] * sc);
#pragma unroll
  for (int j = 0; j < 8; ++j) o1[j] = f2bf(tile[c0 + 8 + j][r] * sc);
  *(ushort8_t*)(Wt + (size_t)(n0 + r) * C_ + k0 + c0) = o0;
  *(ushort8_t*)(Wt + (size_t)(n0 + r) * C_ + k0 + c0 + 8) = o1;
}

// ---- 128x256 ring-3 GEMM for QKV, 4 waves, per-wave 128x64 output (r11) ----
__global__ __launch_bounds__(256, 2) void gemm8_k(const u16* __restrict__ A,
                                                  const u16* __restrict__ Wt,
                                                  const float* __restrict__ b0,
                                                  const float* __restrict__ b1,
                                                  const float* __restrict__ b2,
                                                  float bsc0,
                                                  u16* __restrict__ Cout) {
  __shared__ u16 lds3[36864];   // 3 slots x 12288 u16 (A 4096 | B 8192)
  const int tid = threadIdx.x;  // 256 thr = 4 waves; wave = N-quadrant
  const int lane = tid & 63, wn = tid >> 6;
  const int l15 = lane & 15, g = lane >> 4;

  const int bid = blockIdx.x;                 // 768 = 8 XCD chunks of 96
  const int swz = (bid & 7) * 96 + (bid >> 3);
  const int bn = swz >> 6, bm = swz & 63;     // bn-major: XCD chunk shares B
  const int m0 = bm * 128, n0 = bn * 256;

  const int srow = tid >> 2;                  // 0..63
  const int scol = ((tid & 3) ^ ((srow >> 1) & 3)) * 8;   // pre-swizzled source
  const u16* gA = A  + (size_t)(m0 + srow) * 1024 + scol;
  const u16* gB = Wt + (size_t)(n0 + srow) * 1024 + scol;

#define STAGE(KT) do { \
    u16* s_ = lds3 + ((KT) % 3) * 12288; \
    gload16(gA + (KT) * 32,                      s_ + tid * 8); \
    gload16(gA + (size_t)64 * 1024 + (KT) * 32,  s_ + 2048 + tid * 8); \
    gload16(gB + (KT) * 32,                      s_ + 4096 + tid * 8); \
    gload16(gB + (size_t)64 * 1024 + (KT) * 32,  s_ + 6144 + tid * 8); \
    gload16(gB + (size_t)128 * 1024 + (KT) * 32, s_ + 8192 + tid * 8); \
    gload16(gB + (size_t)192 * 1024 + (KT) * 32, s_ + 10240 + tid * 8); \
  } while (0)

  floatx4 acc[8][4] = {};

  STAGE(0);
  STAGE(1);

  for (int kt = 0; kt < 32; ++kt) {
    if (kt < 31) asm volatile("s_waitcnt vmcnt(6)" ::: "memory");
    else         asm volatile("s_waitcnt vmcnt(0)" ::: "memory");
    __builtin_amdgcn_s_barrier();
    __builtin_amdgcn_sched_barrier(0);
    if (kt < 30) STAGE(kt + 2);

    const u16* Ab = lds3 + (kt % 3) * 12288;
    const u16* Bb = Ab + 4096;
    short8 af[8], bf[4];
#pragma unroll
    for (int mi = 0; mi < 8; ++mi) {
      int ra = mi * 16 + l15;
      af[mi] = *(const short8*)(Ab + ra * 32 + ((g ^ ((ra >> 1) & 3)) << 3));
    }
#pragma unroll
    for (int ni = 0; ni < 4; ++ni) {
      int rb = wn * 64 + ni * 16 + l15;
      bf[ni] = *(const short8*)(Bb + rb * 32 + ((g ^ ((rb >> 1) & 3)) << 3));
    }
    __builtin_amdgcn_s_setprio(1);
#pragma unroll
    for (int mi = 0; mi < 8; ++mi)
#pragma unroll
      for (int ni = 0; ni < 4; ++ni)
        acc[mi][ni] = MFMA16(af[mi], bf[ni], acc[mi][ni]);
    __builtin_amdgcn_s_setprio(0);
  }

#pragma unroll
  for (int mi = 0; mi < 8; ++mi) {
    int row = m0 + mi * 16 + g * 4;
#pragma unroll
    for (int ni = 0; ni < 4; ++ni) {
      int col = n0 + wn * 64 + ni * 16 + l15;
      int seg = col >> 10;
      const float* bp = seg == 0 ? b0 : seg == 1 ? b1 : b2;
      float bv = bp[col & 1023] * (seg == 0 ? bsc0 : 1.0f);
#pragma unroll
      for (int i = 0; i < 4; ++i)
        Cout[(size_t)(row + i) * CR3 + col] = f2bf(acc[mi][ni][i] + bv);
    }
  }
}

// ---- V^T pre-transpose: QKVb V-cols -> Vtg[bh][d][kv] (16 MB) (r10) --------
__global__ __launch_bounds__(256) void vt_k(const u16* __restrict__ QKV,
                                            u16* __restrict__ Vtg) {
  __shared__ unsigned tl[64][65];
  const int tid = threadIdx.x;
  const int bx = blockIdx.x, by = blockIdx.y;
  const int r = tid >> 3, c8 = (tid & 7) * 8;
  const size_t inb = ((size_t)(by >> 4) * T_ + (size_t)bx * 64) * CR3 + 2048 + (by & 15) * 64 + c8;
  ushort8_t va = *(const ushort8_t*)(QKV + inb + (size_t)r * CR3);
  ushort8_t vb = *(const ushort8_t*)(QKV + inb + (size_t)(r + 32) * CR3);
#pragma unroll
  for (int j = 0; j < 8; ++j) { tl[r][c8 + j] = va[j]; tl[r + 32][c8 + j] = vb[j]; }
  __syncthreads();
  ushort8_t o0, o1;
#pragma unroll
  for (int j = 0; j < 8; ++j) { o0[j] = (u16)tl[c8 + j][r]; o1[j] = (u16)tl[c8 + j][r + 32]; }
  const size_t ob = ((size_t)by * 64 + r) * 2048 + bx * 64 + c8;
  *(ushort8_t*)(Vtg + ob) = o0;
  *(ushort8_t*)(Vtg + ob + (size_t)32 * 2048) = o1;
}

// ---- GEMM: C[M,N] = A[M,astride]@WT[N,1024]^T + bias, 128x128 (out proj) ---
template <int OUTF32>
__global__ __launch_bounds__(256, 2) void gemm_k(const u16* __restrict__ A,
                                                 int astride,
                                                 const u16* __restrict__ Wt,
                                                 const float* __restrict__ b0,
                                                 void* __restrict__ Cout, int ostride) {
  __shared__ u16 As[128 * 32];
  __shared__ u16 Bs[128 * 32];
  const int tid = threadIdx.x;
  const int w = tid >> 6, lane = tid & 63;
  const int wr = (w >> 1) * 64, wc = (w & 1) * 64;
  const int l15 = lane & 15, g = lane >> 4;
  const int m0 = blockIdx.x * 128, n0 = blockIdx.y * 128;

  floatx4 acc[4][4] = {};

  const int srow = tid >> 2;
  const int scol = ((tid & 3) ^ ((srow >> 1) & 3)) * 8;
  const u16* ga = A + (size_t)(m0 + srow) * astride + scol;
  const u16* gb = Wt + (size_t)(n0 + srow) * C_ + scol;
  u16* lA = As + tid * 8;
  u16* lB = Bs + tid * 8;

  for (int kt = 0; kt < C_; kt += 32) {
    gload16(ga + kt, lA);
    gload16(ga + kt + (size_t)64 * astride, lA + 64 * 32);
    gload16(gb + kt, lB);
    gload16(gb + kt + (size_t)64 * C_, lB + 64 * 32);
    asm volatile("s_waitcnt vmcnt(0)" ::: "memory");
    __syncthreads();
    short8 af[4], bf[4];
#pragma unroll
    for (int i = 0; i < 4; ++i) {
      int ra = wr + i * 16 + l15;
      af[i] = *(const short8*)(As + ra * 32 + ((g ^ ((ra >> 1) & 3)) << 3));
    }
#pragma unroll
    for (int i = 0; i < 4; ++i) {
      int rb = wc + i * 16 + l15;
      bf[i] = *(const short8*)(Bs + rb * 32 + ((g ^ ((rb >> 1) & 3)) << 3));
    }
#pragma unroll
    for (int mi = 0; mi < 4; ++mi)
#pragma unroll
      for (int ni = 0; ni < 4; ++ni)
        acc[mi][ni] = MFMA16(af[mi], bf[ni], acc[mi][ni]);
    __syncthreads();
  }
#pragma unroll
  for (int mi = 0; mi < 4; ++mi) {
    int row = m0 + wr + mi * 16 + g * 4;
#pragma unroll
    for (int ni = 0; ni < 4; ++ni) {
      int col = n0 + wc + ni * 16 + l15;
      float bv = b0[col];
#pragma unroll
      for (int i = 0; i < 4; ++i) {
        float v = acc[mi][ni][i] + bv;
        if (OUTF32)
          ((float*)Cout)[(size_t)(row + i) * ostride + col] = v;
        else
          ((u16*)Cout)[(size_t)(row + i) * ostride + col] = f2bf(v);
      }
    }
  }
}

// ------------- causal flash attention: barrier-free per-wave streaming ------
// 512 blocks x 256 thr; each WAVE independently owns q-tile pair (p, 63-p) of
// one head: 65 kv-tile computes, ALWAYS (uniform). KVBLK=32, 32 q-rows/wave.
// K and V^T MFMA fragments loaded DIRECTLY global->VGPR (16B/lane contiguous;
// formulas identical to prior verified LDS reads). Register double-buffer
// (named A/B sets, rule 20). No LDS, no s_barrier, no cross-wave coupling.
// Heads XCD-chunked: blocks b%8==x -> heads x*8..x*8+7 (K/V 4MB = XCD L2).
// Y written into QKVb's dead V-columns (stride CR3).
__global__ __launch_bounds__(256, 2) void attn_k(u16* __restrict__ QKV,
                                                 const u16* __restrict__ Vtg) {
  const int tid = threadIdx.x;
  const int w = tid >> 6, lane = tid & 63;
  const int qi = lane & 31, h = lane >> 5;

  const int b = blockIdx.x;                       // 512
  const int bh = (b & 7) * 8 + ((b >> 3) & 7);    // head, XCD-chunked
  const int p = (b >> 6) * 4 + w;                 // fold pair 0..31

  const size_t baseQ = (size_t)(bh >> 4) * T_ * CR3 + (size_t)(bh & 15) * D_;
  const u16* Kl = QKV + baseQ + 1024 + (size_t)qi * CR3 + h * 8;   // K frag base
  const u16* Vl = Vtg + (size_t)bh * (64 * 2048) + (size_t)qi * 2048 + h * 8;

  short8 qf0, qf1, qf2, qf3;
  short8 kA0, kA1, kA2, kA3, vA0, vA1, vA2, vA3;
  short8 kB0, kB1, kB2, kB3, vB0, vB1, vB2, vB3;
  f32x16 y0, y1;
  float l_run;

#define PRE(S, T) do { \
    const u16* kp_ = Kl + (size_t)(T) * 32 * CR3; \
    k##S##0 = *(const short8*)(kp_); \
    k##S##1 = *(const short8*)(kp_ + 16); \
    k##S##2 = *(const short8*)(kp_ + 32); \
    k##S##3 = *(const short8*)(kp_ + 48); \
    const u16* vp_ = Vl + (T) * 32; \
    v##S##0 = *(const short8*)(vp_); \
    v##S##1 = *(const short8*)(vp_ + 16); \
    v##S##2 = *(const short8*)(vp_ + (size_t)32 * 2048); \
    v##S##3 = *(const short8*)(vp_ + (size_t)32 * 2048 + 16); \
  } while (0)

#define COMP(S, KV0, DIAG) do { \
    f32x16 s = {}; \
    s = MFMA32(k##S##0, qf0, s); \
    s = MFMA32(k##S##1, qf1, s); \
    s = MFMA32(k##S##2, qf2, s); \
    s = MFMA32(k##S##3, qf3, s); \
    if (DIAG) { \
      _Pragma("unroll") for (int r = 0; r < 16; ++r) { \
        int kvq_ = (r & 3) + 8 * (r >> 2) + 4 * h; \
        if ((KV0) + kvq_ > q_abs) s[r] = -1e30f; \
      } \
    } \
    _Pragma("unroll") for (int r = 0; r < 16; ++r) s[r] = __builtin_amdgcn_exp2f(s[r] - 13.0f); \
    { float a8_[8]; \
      _Pragma("unroll") for (int r = 0; r < 8; ++r) a8_[r] = s[r] + s[r + 8]; \
      _Pragma("unroll") for (int r = 0; r < 4; ++r) a8_[r] += a8_[r + 4]; \
      l_run += (a8_[0] + a8_[1]) + (a8_[2] + a8_[3]); } \
    unsigned pw_[8]; \
    { unsigned a0_, b0_, a1_, b1_; \
      a0_ = cvtpk(s[0], s[1]);  b0_ = cvtpk(s[4], s[5]);  pl32swap(a0_, b0_); \
      a1_ = cvtpk(s[2], s[3]);  b1_ = cvtpk(s[6], s[7]);  pl32swap(a1_, b1_); \
      pw_[0] = a0_; pw_[1] = a1_; pw_[2] = b0_; pw_[3] = b1_; \
      a0_ = cvtpk(s[8], s[9]);  b0_ = cvtpk(s[12], s[13]); pl32swap(a0_, b0_); \
      a1_ = cvtpk(s[10], s[11]); b1_ = cvtpk(s[14], s[15]); pl32swap(a1_, b1_); \
      pw_[4] = a0_; pw_[5] = a1_; pw_[6] = b0_; pw_[7] = b1_; } \
    { uint4_t p0_ = {pw_[0], pw_[1], pw_[2], pw_[3]}; \
      uint4_t p1_ = {pw_[4], pw_[5], pw_[6], pw_[7]}; \
      short8 pa0_ = __builtin_bit_cast(short8, p0_); \
      short8 pa1_ = __builtin_bit_cast(short8, p1_); \
      y0 = MFMA32(pa0_, v##S##0, y0); \
      y0 = MFMA32(pa1_, v##S##1, y0); \
      y1 = MFMA32(pa0_, v##S##2, y1); \
      y1 = MFMA32(pa1_, v##S##3, y1); } \
  } while (0)

  for (int ph = 0; ph < 2; ++ph) {
    const int j = ph ? (63 - p) : p;
    const int ntt = j + 1;
    const int qw0 = 32 * j;
    const int q_abs = qw0 + qi;
    {
      const u16* Qr = QKV + baseQ + (size_t)q_abs * CR3 + 8 * h;
      qf0 = *(const short8*)(Qr);      qf1 = *(const short8*)(Qr + 16);
      qf2 = *(const short8*)(Qr + 32); qf3 = *(const short8*)(Qr + 48);
    }
    y0 = (f32x16){};
    y1 = (f32x16){};
    l_run = 0.f;

    PRE(A, 0);
    if (ntt > 1) PRE(B, 1);
    for (int t = 0; t < ntt; t += 2) {
      COMP(A, t * 32, t == j);
      if (t + 2 < ntt) PRE(A, t + 2);
      if (t + 1 < ntt) {
        COMP(B, (t + 1) * 32, t + 1 == j);
        if (t + 3 < ntt) PRE(B, t + 3);
      }
    }

    l_run += __shfl_xor(l_run, 32);
    float linv = 1.0f / l_run;
    const size_t baseY = baseQ + 2048;
#pragma unroll
    for (int r = 0; r < 16; ++r) {
      int qp = (r & 3) + 8 * (r >> 2) + 4 * h;
      float lv = __shfl(linv, qp);
      size_t row = baseY + (size_t)(qw0 + qp) * CR3;
      QKV[row + qi] = f2bf(y0[r] * lv);
      QKV[row + 32 + qi] = f2bf(y1[r] * lv);
    }
  }
}

extern "C" void kernel_launch(void* const* d_in, const int* in_sizes, int n_in,
                              void* d_out, int out_size, void* d_ws, size_t ws_size,
                              hipStream_t stream) {
  const float* x  = (const float*)d_in[0];
  const float* Wq = (const float*)d_in[1];
  const float* bq = (const float*)d_in[2];
  const float* Wk = (const float*)d_in[3];
  const float* bk = (const float*)d_in[4];
  const float* Wv = (const float*)d_in[5];
  const float* bv = (const float*)d_in[6];
  const float* Wo = (const float*)d_in[7];
  const float* bo = (const float*)d_in[8];
  float* out = (float*)d_out;

  char* ws = (char*)d_ws;
  u16* xb   = (u16*)ws;                           // 16 MiB: x-bf16, later Vtg
  u16* WT   = (u16*)(ws + (size_t)16777216);      // 4 x 2 MiB
  u16* QKVb = (u16*)(ws + (size_t)25165824);      // 48 MiB (V-cols become Y)
  u16* Vtg  = xb;                                 // V^T overlays dead x-bf16

  convx_k<<<dim3(M_ * C_ / 1024), 256, 0, stream>>>(x, xb);
  wconv_k<<<dim3(16, 16, 4), 256, 0, stream>>>(Wq, Wk, Wv, Wo, WT);
  gemm8_k<<<dim3(768), 256, 0, stream>>>(xb, WT, bq, bk, bv, 0.125f * 1.44269504f, QKVb);
  vt_k<<<dim3(32, 64), 256, 0, stream>>>(QKVb, Vtg);
  attn_k<<<dim3(512), 256, 0, stream>>>(QKVb, Vtg);
  gemm_k<1><<<dim3(64, 8), 256, 0, stream>>>(QKVb + 2048, CR3, WT + (size_t)3 * 1048576,
                                             bo, out, C_);
}

// Round 13
// 176.755 us; speedup vs baseline: 1.3156x; 1.3156x over previous
//
#include <hip/hip_runtime.h>

#define B_ 4
#define T_ 2048
#define C_ 1024
#define H_ 16
#define D_ 64
#define M_ (B_*T_)   // 8192 rows
#define CR3 3072     // fused QKV row stride

typedef unsigned short u16;
typedef __attribute__((ext_vector_type(8))) short short8;
typedef __attribute__((ext_vector_type(8))) unsigned short ushort8_t;
typedef __attribute__((ext_vector_type(4))) unsigned short ushort4_t;
typedef __attribute__((ext_vector_type(4))) float floatx4;
typedef __attribute__((ext_vector_type(16))) float f32x16;
typedef __attribute__((ext_vector_type(4))) unsigned int uint4_t;

__device__ __forceinline__ u16 f2bf(float f) {
  union { float f; unsigned u; } v; v.f = f;
  unsigned r = v.u + 0x7fffu + ((v.u >> 16) & 1u);
  return (u16)(r >> 16);
}

__device__ __forceinline__ void gload16(const void* g, void* l) {
  __builtin_amdgcn_global_load_lds((__attribute__((address_space(1))) void*)(g),
                                   (__attribute__((address_space(3))) void*)(l),
                                   16, 0, 0);
}

__device__ __forceinline__ unsigned cvtpk(float lo, float hi) {
  unsigned r;
  asm("v_cvt_pk_bf16_f32 %0, %1, %2" : "=v"(r) : "v"(lo), "v"(hi));
  return r;
}

__device__ __forceinline__ void pl32swap(unsigned &a, unsigned &b) {
  asm volatile("v_permlane32_swap_b32 %0, %1" : "+v"(a), "+v"(b));
}

#define MFMA32(a, b, c) __builtin_amdgcn_mfma_f32_32x32x16_bf16(a, b, c, 0, 0, 0)
#define MFMA16(a, b, c) __builtin_amdgcn_mfma_f32_16x16x32_bf16(a, b, c, 0, 0, 0)

// ---------------- x -> bf16 ----------------
__global__ __launch_bounds__(256) void convx_k(const float* __restrict__ x,
                                               u16* __restrict__ o) {
  int i = (blockIdx.x * 256 + threadIdx.x) * 4;
  floatx4 v = *(const floatx4*)(x + i);
  ushort4_t r;
#pragma unroll
  for (int j = 0; j < 4; ++j) r[j] = f2bf(v[j]);
  *(ushort4_t*)(o + i) = r;
}

// ------------- W (K x N) -> WT (N x K) bf16 (Wq pre-scaled), LDS transpose ----
__global__ __launch_bounds__(256) void wconv_k(const float* __restrict__ W0,
                                               const float* __restrict__ W1,
                                               const float* __restrict__ W2,
                                               const float* __restrict__ W3,
                                               u16* __restrict__ WT) {
  __shared__ float tile[64][65];
  const float* W = blockIdx.z == 0 ? W0 : blockIdx.z == 1 ? W1 : blockIdx.z == 2 ? W2 : W3;
  const float sc = blockIdx.z == 0 ? 0.125f * 1.44269504f : 1.0f;  // 1/sqrt(D)*log2e into Wq
  u16* Wt = WT + (size_t)blockIdx.z * (C_ * C_);
  int k0 = blockIdx.x * 64, n0 = blockIdx.y * 64;
  int t = threadIdx.x;
  int r = t >> 2, c0 = (t & 3) * 16;
#pragma unroll
  for (int j = 0; j < 4; ++j) {
    floatx4 v = *(const floatx4*)(W + (size_t)(k0 + r) * C_ + n0 + c0 + j * 4);
#pragma unroll
    for (int jj = 0; jj < 4; ++jj) tile[r][c0 + j * 4 + jj] = v[jj];
  }
  __syncthreads();
  ushort8_t o0, o1;
#pragma unroll
  for (int j = 0; j < 8; ++j) o0[j] = f2bf(tile[c0 + j][r] * sc);
#pragma unroll
  for (int j = 0; j < 8; ++j) o1[j] = f2bf(tile[c0 + 8 + j][r] * sc);
  *(ushort8_t*)(Wt + (size_t)(n0 + r) * C_ + k0 + c0) = o0;
  *(ushort8_t*)(Wt + (size_t)(n0 + r) * C_ + k0 + c0 + 8) = o1;
}

// ---- 128x256 ring-3 GEMM for QKV, 4 waves, per-wave 128x64 output (r11) ----
__global__ __launch_bounds__(256, 2) void gemm8_k(const u16* __restrict__ A,
                                                  const u16* __restrict__ Wt,
                                                  const float* __restrict__ b0,
                                                  const float* __restrict__ b1,
                                                  const float* __restrict__ b2,
                                                  float bsc0,
                                                  u16* __restrict__ Cout) {
  __shared__ u16 lds3[36864];   // 3 slots x 12288 u16 (A 4096 | B 8192)
  const int tid = threadIdx.x;
  const int lane = tid & 63, wn = tid >> 6;
  const int l15 = lane & 15, g = lane >> 4;

  const int bid = blockIdx.x;                 // 768 = 8 XCD chunks of 96
  const int swz = (bid & 7) * 96 + (bid >> 3);
  const int bn = swz >> 6, bm = swz & 63;
  const int m0 = bm * 128, n0 = bn * 256;

  const int srow = tid >> 2;
  const int scol = ((tid & 3) ^ ((srow >> 1) & 3)) * 8;
  const u16* gA = A  + (size_t)(m0 + srow) * 1024 + scol;
  const u16* gB = Wt + (size_t)(n0 + srow) * 1024 + scol;

#define STAGE(KT) do { \
    u16* s_ = lds3 + ((KT) % 3) * 12288; \
    gload16(gA + (KT) * 32,                      s_ + tid * 8); \
    gload16(gA + (size_t)64 * 1024 + (KT) * 32,  s_ + 2048 + tid * 8); \
    gload16(gB + (KT) * 32,                      s_ + 4096 + tid * 8); \
    gload16(gB + (size_t)64 * 1024 + (KT) * 32,  s_ + 6144 + tid * 8); \
    gload16(gB + (size_t)128 * 1024 + (KT) * 32, s_ + 8192 + tid * 8); \
    gload16(gB + (size_t)192 * 1024 + (KT) * 32, s_ + 10240 + tid * 8); \
  } while (0)

  floatx4 acc[8][4] = {};

  STAGE(0);
  STAGE(1);

  for (int kt = 0; kt < 32; ++kt) {
    if (kt < 31) asm volatile("s_waitcnt vmcnt(6)" ::: "memory");
    else         asm volatile("s_waitcnt vmcnt(0)" ::: "memory");
    __builtin_amdgcn_s_barrier();
    __builtin_amdgcn_sched_barrier(0);
    if (kt < 30) STAGE(kt + 2);

    const u16* Ab = lds3 + (kt % 3) * 12288;
    const u16* Bb = Ab + 4096;
    short8 af[8], bf[4];
#pragma unroll
    for (int mi = 0; mi < 8; ++mi) {
      int ra = mi * 16 + l15;
      af[mi] = *(const short8*)(Ab + ra * 32 + ((g ^ ((ra >> 1) & 3)) << 3));
    }
#pragma unroll
    for (int ni = 0; ni < 4; ++ni) {
      int rb = wn * 64 + ni * 16 + l15;
      bf[ni] = *(const short8*)(Bb + rb * 32 + ((g ^ ((rb >> 1) & 3)) << 3));
    }
    __builtin_amdgcn_s_setprio(1);
#pragma unroll
    for (int mi = 0; mi < 8; ++mi)
#pragma unroll
      for (int ni = 0; ni < 4; ++ni)
        acc[mi][ni] = MFMA16(af[mi], bf[ni], acc[mi][ni]);
    __builtin_amdgcn_s_setprio(0);
  }

#pragma unroll
  for (int mi = 0; mi < 8; ++mi) {
    int row = m0 + mi * 16 + g * 4;
#pragma unroll
    for (int ni = 0; ni < 4; ++ni) {
      int col = n0 + wn * 64 + ni * 16 + l15;
      int seg = col >> 10;
      const float* bp = seg == 0 ? b0 : seg == 1 ? b1 : b2;
      float bv = bp[col & 1023] * (seg == 0 ? bsc0 : 1.0f);
#pragma unroll
      for (int i = 0; i < 4; ++i)
        Cout[(size_t)(row + i) * CR3 + col] = f2bf(acc[mi][ni][i] + bv);
    }
  }
}

// ---- V^T pre-transpose: QKVb V-cols -> Vtg[bh][d][kv] (16 MB) (r10) --------
__global__ __launch_bounds__(256) void vt_k(const u16* __restrict__ QKV,
                                            u16* __restrict__ Vtg) {
  __shared__ unsigned tl[64][65];
  const int tid = threadIdx.x;
  const int bx = blockIdx.x, by = blockIdx.y;
  const int r = tid >> 3, c8 = (tid & 7) * 8;
  const size_t inb = ((size_t)(by >> 4) * T_ + (size_t)bx * 64) * CR3 + 2048 + (by & 15) * 64 + c8;
  ushort8_t va = *(const ushort8_t*)(QKV + inb + (size_t)r * CR3);
  ushort8_t vb = *(const ushort8_t*)(QKV + inb + (size_t)(r + 32) * CR3);
#pragma unroll
  for (int j = 0; j < 8; ++j) { tl[r][c8 + j] = va[j]; tl[r + 32][c8 + j] = vb[j]; }
  __syncthreads();
  ushort8_t o0, o1;
#pragma unroll
  for (int j = 0; j < 8; ++j) { o0[j] = (u16)tl[c8 + j][r]; o1[j] = (u16)tl[c8 + j][r + 32]; }
  const size_t ob = ((size_t)by * 64 + r) * 2048 + bx * 64 + c8;
  *(ushort8_t*)(Vtg + ob) = o0;
  *(ushort8_t*)(Vtg + ob + (size_t)32 * 2048) = o1;
}

// ---- out-proj: 128x256, gemm8 ring-3 structure, A stride CR3, f32 out ------
__global__ __launch_bounds__(256, 2) void gemmO_k(const u16* __restrict__ A,
                                                  const u16* __restrict__ Wt,
                                                  const float* __restrict__ b0,
                                                  float* __restrict__ Cout) {
  __shared__ u16 lds3[36864];
  const int tid = threadIdx.x;
  const int lane = tid & 63, wn = tid >> 6;
  const int l15 = lane & 15, g = lane >> 4;

  const int bid = blockIdx.x;                 // 256 = 8 XCD chunks of 32
  const int swz = (bid & 7) * 32 + (bid >> 3);
  const int bn = swz >> 6, bm = swz & 63;     // 64 M x 4 N
  const int m0 = bm * 128, n0 = bn * 256;

  const int srow = tid >> 2;
  const int scol = ((tid & 3) ^ ((srow >> 1) & 3)) * 8;
  const u16* gA = A  + (size_t)(m0 + srow) * CR3 + scol;
  const u16* gB = Wt + (size_t)(n0 + srow) * 1024 + scol;

#define STAGEO(KT) do { \
    u16* s_ = lds3 + ((KT) % 3) * 12288; \
    gload16(gA + (KT) * 32,                      s_ + tid * 8); \
    gload16(gA + (size_t)64 * CR3 + (KT) * 32,   s_ + 2048 + tid * 8); \
    gload16(gB + (KT) * 32,                      s_ + 4096 + tid * 8); \
    gload16(gB + (size_t)64 * 1024 + (KT) * 32,  s_ + 6144 + tid * 8); \
    gload16(gB + (size_t)128 * 1024 + (KT) * 32, s_ + 8192 + tid * 8); \
    gload16(gB + (size_t)192 * 1024 + (KT) * 32, s_ + 10240 + tid * 8); \
  } while (0)

  floatx4 acc[8][4] = {};

  STAGEO(0);
  STAGEO(1);

  for (int kt = 0; kt < 32; ++kt) {
    if (kt < 31) asm volatile("s_waitcnt vmcnt(6)" ::: "memory");
    else         asm volatile("s_waitcnt vmcnt(0)" ::: "memory");
    __builtin_amdgcn_s_barrier();
    __builtin_amdgcn_sched_barrier(0);
    if (kt < 30) STAGEO(kt + 2);

    const u16* Ab = lds3 + (kt % 3) * 12288;
    const u16* Bb = Ab + 4096;
    short8 af[8], bf[4];
#pragma unroll
    for (int mi = 0; mi < 8; ++mi) {
      int ra = mi * 16 + l15;
      af[mi] = *(const short8*)(Ab + ra * 32 + ((g ^ ((ra >> 1) & 3)) << 3));
    }
#pragma unroll
    for (int ni = 0; ni < 4; ++ni) {
      int rb = wn * 64 + ni * 16 + l15;
      bf[ni] = *(const short8*)(Bb + rb * 32 + ((g ^ ((rb >> 1) & 3)) << 3));
    }
    __builtin_amdgcn_s_setprio(1);
#pragma unroll
    for (int mi = 0; mi < 8; ++mi)
#pragma unroll
      for (int ni = 0; ni < 4; ++ni)
        acc[mi][ni] = MFMA16(af[mi], bf[ni], acc[mi][ni]);
    __builtin_amdgcn_s_setprio(0);
  }

#pragma unroll
  for (int mi = 0; mi < 8; ++mi) {
    int row = m0 + mi * 16 + g * 4;
#pragma unroll
    for (int ni = 0; ni < 4; ++ni) {
      int col = n0 + wn * 64 + ni * 16 + l15;
      float bv = b0[col];
#pragma unroll
      for (int i = 0; i < 4; ++i)
        Cout[(size_t)(row + i) * 1024 + col] = acc[mi][ni][i] + bv;
    }
  }
}

// ------------- causal flash attention: per-wave LDS streaming, barrier-free --
// 512 blocks x 4 waves; each WAVE owns q-tile pair (p, 63-p) of one head:
// 65 kv-tiles, uniform. KVBLK=32. Per-wave ring-2 LDS (K 4KB + V^T 4KB per
// slot, 16KB/wave, 64KB/block -> 2 blocks/CU). Staging via 8 coalesced
// global_load_lds per tile; per-wave counted vmcnt(8)/(0); NO s_barrier.
// lgkmcnt(0)+sched_barrier fence before each in-loop stage guards the ring-2
// overwrite (replaces barrier guarantee). Fragment math = r12 (refcheck'd).
// K LDS swizzle: chunk^=(row&7); V^T: chunk^=((row>>3)&3) (involutions, both
// sides). Y written into QKVb's dead V-columns (stride CR3).
__global__ __launch_bounds__(256, 2) void attn_k(u16* __restrict__ QKV,
                                                 const u16* __restrict__ Vtg) {
  __shared__ u16 alds[32768];   // 4 waves x 2 slots x (K 2048 + V 2048) u16
  const int tid = threadIdx.x;
  const int w = tid >> 6, lane = tid & 63;
  const int qi = lane & 31, h = lane >> 5;

  const int b = blockIdx.x;                       // 512
  const int bh = (b & 7) * 8 + ((b >> 3) & 7);    // head, XCD-chunked
  const int p = (b >> 6) * 4 + w;                 // fold pair 0..31

  const size_t baseQ = (size_t)(bh >> 4) * T_ * CR3 + (size_t)(bh & 15) * D_;
  u16* ldsW = alds + w * 8192;                    // this wave's 16KB

  // staging source bases (lane-constant; audited vs read involutions)
  const int kr0 = lane >> 3, kc0 = lane & 7;      // K: row0 0..7, chunk 0..7
  const u16* KgL = QKV + baseQ + 1024 + (size_t)kr0 * CR3 + ((kc0 ^ kr0) * 8);
  const int vr0 = lane >> 2, vc0 = lane & 3, vr5 = lane >> 5;  // V: row0 0..15
  const u16* VgB = Vtg + (size_t)bh * 131072;
  const u16* VgL0 = VgB + (size_t)(vr0) * 2048      + ((vc0 ^ ((0 + vr5) & 3)) * 8);
  const u16* VgL1 = VgB + (size_t)(16 + vr0) * 2048 + ((vc0 ^ ((2 + vr5) & 3)) * 8);
  const u16* VgL2 = VgB + (size_t)(32 + vr0) * 2048 + ((vc0 ^ ((0 + vr5) & 3)) * 8);
  const u16* VgL3 = VgB + (size_t)(48 + vr0) * 2048 + ((vc0 ^ ((2 + vr5) & 3)) * 8);

#define APRE(SLOT, T) do { \
    u16* kd_ = ldsW + (SLOT) * 4096; \
    u16* vd_ = kd_ + 2048; \
    const u16* kp_ = KgL + (size_t)((T) * 32) * CR3; \
    gload16(kp_,                      kd_ + lane * 8); \
    gload16(kp_ + (size_t)8 * CR3,    kd_ + 512 + lane * 8); \
    gload16(kp_ + (size_t)16 * CR3,   kd_ + 1024 + lane * 8); \
    gload16(kp_ + (size_t)24 * CR3,   kd_ + 1536 + lane * 8); \
    gload16(VgL0 + (T) * 32,          vd_ + lane * 8); \
    gload16(VgL1 + (T) * 32,          vd_ + 512 + lane * 8); \
    gload16(VgL2 + (T) * 32,          vd_ + 1024 + lane * 8); \
    gload16(VgL3 + (T) * 32,          vd_ + 1536 + lane * 8); \
  } while (0)

#define AFENCE() do { \
    asm volatile("s_waitcnt lgkmcnt(0)" ::: "memory"); \
    __builtin_amdgcn_sched_barrier(0); \
  } while (0)

  short8 qf0, qf1, qf2, qf3;
  f32x16 y0, y1;
  float l_run;

#define ACOMP(SLOT, KV0, DIAG) do { \
    const char* kb_ = (const char*)(ldsW + (SLOT) * 4096); \
    const int swq_ = (qi & 7) << 4; \
    const char* kr_ = kb_ + qi * 128; \
    short8 k0_ = *(const short8*)(kr_ + ((16 * h) ^ swq_)); \
    short8 k1_ = *(const short8*)(kr_ + ((32 + 16 * h) ^ swq_)); \
    short8 k2_ = *(const short8*)(kr_ + ((64 + 16 * h) ^ swq_)); \
    short8 k3_ = *(const short8*)(kr_ + ((96 + 16 * h) ^ swq_)); \
    f32x16 s = {}; \
    s = MFMA32(k0_, qf0, s); \
    s = MFMA32(k1_, qf1, s); \
    s = MFMA32(k2_, qf2, s); \
    s = MFMA32(k3_, qf3, s); \
    if (DIAG) { \
      _Pragma("unroll") for (int r = 0; r < 16; ++r) { \
        int kvq_ = (r & 3) + 8 * (r >> 2) + 4 * h; \
        if ((KV0) + kvq_ > q_abs) s[r] = -1e30f; \
      } \
    } \
    _Pragma("unroll") for (int r = 0; r < 16; ++r) s[r] = __builtin_amdgcn_exp2f(s[r] - 13.0f); \
    { float a8_[8]; \
      _Pragma("unroll") for (int r = 0; r < 8; ++r) a8_[r] = s[r] + s[r + 8]; \
      _Pragma("unroll") for (int r = 0; r < 4; ++r) a8_[r] += a8_[r + 4]; \
      l_run += (a8_[0] + a8_[1]) + (a8_[2] + a8_[3]); } \
    unsigned pw_[8]; \
    { unsigned a0_, b0_, a1_, b1_; \
      a0_ = cvtpk(s[0], s[1]);  b0_ = cvtpk(s[4], s[5]);  pl32swap(a0_, b0_); \
      a1_ = cvtpk(s[2], s[3]);  b1_ = cvtpk(s[6], s[7]);  pl32swap(a1_, b1_); \
      pw_[0] = a0_; pw_[1] = a1_; pw_[2] = b0_; pw_[3] = b1_; \
      a0_ = cvtpk(s[8], s[9]);  b0_ = cvtpk(s[12], s[13]); pl32swap(a0_, b0_); \
      a1_ = cvtpk(s[10], s[11]); b1_ = cvtpk(s[14], s[15]); pl32swap(a1_, b1_); \
      pw_[4] = a0_; pw_[5] = a1_; pw_[6] = b0_; pw_[7] = b1_; } \
    { const char* vb_ = (const char*)(ldsW + (SLOT) * 4096 + 2048); \
      const int sx3_ = (qi >> 3) & 3; \
      short8 v0_ = *(const short8*)(vb_ + qi * 64 + ((h ^ sx3_) << 4)); \
      short8 v1_ = *(const short8*)(vb_ + qi * 64 + (((h + 2) ^ sx3_) << 4)); \
      short8 v2_ = *(const short8*)(vb_ + (qi + 32) * 64 + ((h ^ sx3_) << 4)); \
      short8 v3_ = *(const short8*)(vb_ + (qi + 32) * 64 + (((h + 2) ^ sx3_) << 4)); \
      uint4_t p0_ = {pw_[0], pw_[1], pw_[2], pw_[3]}; \
      uint4_t p1_ = {pw_[4], pw_[5], pw_[6], pw_[7]}; \
      short8 pa0_ = __builtin_bit_cast(short8, p0_); \
      short8 pa1_ = __builtin_bit_cast(short8, p1_); \
      y0 = MFMA32(pa0_, v0_, y0); \
      y0 = MFMA32(pa1_, v1_, y0); \
      y1 = MFMA32(pa0_, v2_, y1); \
      y1 = MFMA32(pa1_, v3_, y1); } \
  } while (0)

#define AWAIT(N) asm volatile("s_waitcnt vmcnt(" #N ")" ::: "memory")

  for (int ph = 0; ph < 2; ++ph) {
    const int j = ph ? (63 - p) : p;
    const int ntt = j + 1;
    const int qw0 = 32 * j;
    const int q_abs = qw0 + qi;
    {
      const u16* Qr = QKV + baseQ + (size_t)q_abs * CR3 + 8 * h;
      qf0 = *(const short8*)(Qr);      qf1 = *(const short8*)(Qr + 16);
      qf2 = *(const short8*)(Qr + 32); qf3 = *(const short8*)(Qr + 48);
    }
    y0 = (f32x16){};
    y1 = (f32x16){};
    l_run = 0.f;

    APRE(0, 0);
    if (ntt > 1) APRE(1, 1);
    for (int t = 0; t < ntt; t += 2) {
      if (t + 1 < ntt) AWAIT(8); else AWAIT(0);
      ACOMP(0, t * 32, t == j);
      if (t + 2 < ntt) { AFENCE(); APRE(0, t + 2); }
      if (t + 1 < ntt) {
        if (t + 2 < ntt) AWAIT(8); else AWAIT(0);
        ACOMP(1, (t + 1) * 32, t + 1 == j);
        if (t + 3 < ntt) { AFENCE(); APRE(1, t + 3); }
      }
    }

    l_run += __shfl_xor(l_run, 32);
    float linv = 1.0f / l_run;
    const size_t baseY = baseQ + 2048;
#pragma unroll
    for (int r = 0; r < 16; ++r) {
      int qp = (r & 3) + 8 * (r >> 2) + 4 * h;
      float lv = __shfl(linv, qp);
      size_t row = baseY + (size_t)(qw0 + qp) * CR3;
      QKV[row + qi] = f2bf(y0[r] * lv);
      QKV[row + 32 + qi] = f2bf(y1[r] * lv);
    }
  }
}

extern "C" void kernel_launch(void* const* d_in, const int* in_sizes, int n_in,
                              void* d_out, int out_size, void* d_ws, size_t ws_size,
                              hipStream_t stream) {
  const float* x  = (const float*)d_in[0];
  const float* Wq = (const float*)d_in[1];
  const float* bq = (const float*)d_in[2];
  const float* Wk = (const float*)d_in[3];
  const float* bk = (const float*)d_in[4];
  const float* Wv = (const float*)d_in[5];
  const float* bv = (const float*)d_in[6];
  const float* Wo = (const float*)d_in[7];
  const float* bo = (const float*)d_in[8];
  float* out = (float*)d_out;

  char* ws = (char*)d_ws;
  u16* xb   = (u16*)ws;                           // 16 MiB: x-bf16, later Vtg
  u16* WT   = (u16*)(ws + (size_t)16777216);      // 4 x 2 MiB
  u16* QKVb = (u16*)(ws + (size_t)25165824);      // 48 MiB (V-cols become Y)
  u16* Vtg  = xb;                                 // V^T overlays dead x-bf16

  convx_k<<<dim3(M_ * C_ / 1024), 256, 0, stream>>>(x, xb);
  wconv_k<<<dim3(16, 16, 4), 256, 0, stream>>>(Wq, Wk, Wv, Wo, WT);
  gemm8_k<<<dim3(768), 256, 0, stream>>>(xb, WT, bq, bk, bv, 0.125f * 1.44269504f, QKVb);
  vt_k<<<dim3(32, 64), 256, 0, stream>>>(QKVb, Vtg);
  attn_k<<<dim3(512), 256, 0, stream>>>(QKVb, Vtg);
  gemmO_k<<<dim3(256), 256, 0, stream>>>(QKVb + 2048, WT + (size_t)3 * 1048576, bo, out);
}

// Round 14
// 163.659 us; speedup vs baseline: 1.4208x; 1.0800x over previous
//
#include <hip/hip_runtime.h>

#define B_ 4
#define T_ 2048
#define C_ 1024
#define H_ 16
#define D_ 64
#define M_ (B_*T_)   // 8192 rows
#define CR3 3072     // fused QKV row stride

typedef unsigned short u16;
typedef __attribute__((ext_vector_type(8))) short short8;
typedef __attribute__((ext_vector_type(8))) unsigned short ushort8_t;
typedef __attribute__((ext_vector_type(4))) unsigned short ushort4_t;
typedef __attribute__((ext_vector_type(4))) float floatx4;
typedef __attribute__((ext_vector_type(16))) float f32x16;
typedef __attribute__((ext_vector_type(4))) unsigned int uint4_t;

__device__ __forceinline__ u16 f2bf(float f) {
  union { float f; unsigned u; } v; v.f = f;
  unsigned r = v.u + 0x7fffu + ((v.u >> 16) & 1u);
  return (u16)(r >> 16);
}

__device__ __forceinline__ void gload16(const void* g, void* l) {
  __builtin_amdgcn_global_load_lds((__attribute__((address_space(1))) void*)(g),
                                   (__attribute__((address_space(3))) void*)(l),
                                   16, 0, 0);
}

__device__ __forceinline__ unsigned cvtpk(float lo, float hi) {
  unsigned r;
  asm("v_cvt_pk_bf16_f32 %0, %1, %2" : "=v"(r) : "v"(lo), "v"(hi));
  return r;
}

__device__ __forceinline__ void pl32swap(unsigned &a, unsigned &b) {
  asm volatile("v_permlane32_swap_b32 %0, %1" : "+v"(a), "+v"(b));
}

#define MFMA32(a, b, c) __builtin_amdgcn_mfma_f32_32x32x16_bf16(a, b, c, 0, 0, 0)
#define MFMA16(a, b, c) __builtin_amdgcn_mfma_f32_16x16x32_bf16(a, b, c, 0, 0, 0)

// ---------------- x -> bf16 ----------------
__global__ __launch_bounds__(256) void convx_k(const float* __restrict__ x,
                                               u16* __restrict__ o) {
  int i = (blockIdx.x * 256 + threadIdx.x) * 4;
  floatx4 v = *(const floatx4*)(x + i);
  ushort4_t r;
#pragma unroll
  for (int j = 0; j < 4; ++j) r[j] = f2bf(v[j]);
  *(ushort4_t*)(o + i) = r;
}

// ------------- W (K x N) -> WT (N x K) bf16 (Wq pre-scaled), LDS transpose ----
__global__ __launch_bounds__(256) void wconv_k(const float* __restrict__ W0,
                                               const float* __restrict__ W1,
                                               const float* __restrict__ W2,
                                               const float* __restrict__ W3,
                                               u16* __restrict__ WT) {
  __shared__ float tile[64][65];
  const float* W = blockIdx.z == 0 ? W0 : blockIdx.z == 1 ? W1 : blockIdx.z == 2 ? W2 : W3;
  const float sc = blockIdx.z == 0 ? 0.125f * 1.44269504f : 1.0f;  // 1/sqrt(D)*log2e into Wq
  u16* Wt = WT + (size_t)blockIdx.z * (C_ * C_);
  int k0 = blockIdx.x * 64, n0 = blockIdx.y * 64;
  int t = threadIdx.x;
  int r = t >> 2, c0 = (t & 3) * 16;
#pragma unroll
  for (int j = 0; j < 4; ++j) {
    floatx4 v = *(const floatx4*)(W + (size_t)(k0 + r) * C_ + n0 + c0 + j * 4);
#pragma unroll
    for (int jj = 0; jj < 4; ++jj) tile[r][c0 + j * 4 + jj] = v[jj];
  }
  __syncthreads();
  ushort8_t o0, o1;
#pragma unroll
  for (int j = 0; j < 8; ++j) o0[j] = f2bf(tile[c0 + j][r] * sc);
#pragma unroll
  for (int j = 0; j < 8; ++j) o1[j] = f2bf(tile[c0 + 8 + j][r] * sc);
  *(ushort8_t*)(Wt + (size_t)(n0 + r) * C_ + k0 + c0) = o0;
  *(ushort8_t*)(Wt + (size_t)(n0 + r) * C_ + k0 + c0 + 8) = o1;
}

// ---- 128x256 ring-3 GEMM for QKV, 4 waves, per-wave 128x64 output (r11) ----
__global__ __launch_bounds__(256, 2) void gemm8_k(const u16* __restrict__ A,
                                                  const u16* __restrict__ Wt,
                                                  const float* __restrict__ b0,
                                                  const float* __restrict__ b1,
                                                  const float* __restrict__ b2,
                                                  float bsc0,
                                                  u16* __restrict__ Cout) {
  __shared__ u16 lds3[36864];   // 3 slots x 12288 u16 (A 4096 | B 8192)
  const int tid = threadIdx.x;  // 256 thr = 4 waves; wave = N-quadrant
  const int lane = tid & 63, wn = tid >> 6;
  const int l15 = lane & 15, g = lane >> 4;

  const int bid = blockIdx.x;                 // 768 = 8 XCD chunks of 96
  const int swz = (bid & 7) * 96 + (bid >> 3);
  const int bn = swz >> 6, bm = swz & 63;     // bn-major: XCD chunk shares B
  const int m0 = bm * 128, n0 = bn * 256;

  const int srow = tid >> 2;                  // 0..63
  const int scol = ((tid & 3) ^ ((srow >> 1) & 3)) * 8;   // pre-swizzled source
  const u16* gA = A  + (size_t)(m0 + srow) * 1024 + scol;
  const u16* gB = Wt + (size_t)(n0 + srow) * 1024 + scol;

#define STAGE(KT) do { \
    u16* s_ = lds3 + ((KT) % 3) * 12288; \
    gload16(gA + (KT) * 32,                      s_ + tid * 8); \
    gload16(gA + (size_t)64 * 1024 + (KT) * 32,  s_ + 2048 + tid * 8); \
    gload16(gB + (KT) * 32,                      s_ + 4096 + tid * 8); \
    gload16(gB + (size_t)64 * 1024 + (KT) * 32,  s_ + 6144 + tid * 8); \
    gload16(gB + (size_t)128 * 1024 + (KT) * 32, s_ + 8192 + tid * 8); \
    gload16(gB + (size_t)192 * 1024 + (KT) * 32, s_ + 10240 + tid * 8); \
  } while (0)

  floatx4 acc[8][4] = {};

  STAGE(0);
  STAGE(1);

  for (int kt = 0; kt < 32; ++kt) {
    if (kt < 31) asm volatile("s_waitcnt vmcnt(6)" ::: "memory");
    else         asm volatile("s_waitcnt vmcnt(0)" ::: "memory");
    __builtin_amdgcn_s_barrier();
    __builtin_amdgcn_sched_barrier(0);
    if (kt < 30) STAGE(kt + 2);   // slot(kt+2)=slot(kt-1): readers done pre-bar

    const u16* Ab = lds3 + (kt % 3) * 12288;
    const u16* Bb = Ab + 4096;
    short8 af[8], bf[4];
#pragma unroll
    for (int mi = 0; mi < 8; ++mi) {
      int ra = mi * 16 + l15;
      af[mi] = *(const short8*)(Ab + ra * 32 + ((g ^ ((ra >> 1) & 3)) << 3));
    }
#pragma unroll
    for (int ni = 0; ni < 4; ++ni) {
      int rb = wn * 64 + ni * 16 + l15;
      bf[ni] = *(const short8*)(Bb + rb * 32 + ((g ^ ((rb >> 1) & 3)) << 3));
    }
    __builtin_amdgcn_s_setprio(1);
#pragma unroll
    for (int mi = 0; mi < 8; ++mi)
#pragma unroll
      for (int ni = 0; ni < 4; ++ni)
        acc[mi][ni] = MFMA16(af[mi], bf[ni], acc[mi][ni]);
    __builtin_amdgcn_s_setprio(0);
  }

#pragma unroll
  for (int mi = 0; mi < 8; ++mi) {
    int row = m0 + mi * 16 + g * 4;
#pragma unroll
    for (int ni = 0; ni < 4; ++ni) {
      int col = n0 + wn * 64 + ni * 16 + l15;
      int seg = col >> 10;
      const float* bp = seg == 0 ? b0 : seg == 1 ? b1 : b2;
      float bv = bp[col & 1023] * (seg == 0 ? bsc0 : 1.0f);
#pragma unroll
      for (int i = 0; i < 4; ++i)
        Cout[(size_t)(row + i) * CR3 + col] = f2bf(acc[mi][ni][i] + bv);
    }
  }
}

// ---- GEMM: C[M,N] = A[M,astride]@WT[N,1024]^T + bias, 128x128 (out proj) ---
template <int OUTF32>
__global__ __launch_bounds__(256, 2) void gemm_k(const u16* __restrict__ A,
                                                 int astride,
                                                 const u16* __restrict__ Wt,
                                                 const float* __restrict__ b0,
                                                 void* __restrict__ Cout, int ostride) {
  __shared__ u16 As[128 * 32];
  __shared__ u16 Bs[128 * 32];
  const int tid = threadIdx.x;
  const int w = tid >> 6, lane = tid & 63;
  const int wr = (w >> 1) * 64, wc = (w & 1) * 64;
  const int l15 = lane & 15, g = lane >> 4;
  const int m0 = blockIdx.x * 128, n0 = blockIdx.y * 128;

  floatx4 acc[4][4] = {};

  const int srow = tid >> 2;
  const int scol = ((tid & 3) ^ ((srow >> 1) & 3)) * 8;
  const u16* ga = A + (size_t)(m0 + srow) * astride + scol;
  const u16* gb = Wt + (size_t)(n0 + srow) * C_ + scol;
  u16* lA = As + tid * 8;
  u16* lB = Bs + tid * 8;

  for (int kt = 0; kt < C_; kt += 32) {
    gload16(ga + kt, lA);
    gload16(ga + kt + (size_t)64 * astride, lA + 64 * 32);
    gload16(gb + kt, lB);
    gload16(gb + kt + (size_t)64 * C_, lB + 64 * 32);
    asm volatile("s_waitcnt vmcnt(0)" ::: "memory");
    __syncthreads();
    short8 af[4], bf[4];
#pragma unroll
    for (int i = 0; i < 4; ++i) {
      int ra = wr + i * 16 + l15;
      af[i] = *(const short8*)(As + ra * 32 + ((g ^ ((ra >> 1) & 3)) << 3));
    }
#pragma unroll
    for (int i = 0; i < 4; ++i) {
      int rb = wc + i * 16 + l15;
      bf[i] = *(const short8*)(Bs + rb * 32 + ((g ^ ((rb >> 1) & 3)) << 3));
    }
#pragma unroll
    for (int mi = 0; mi < 4; ++mi)
#pragma unroll
      for (int ni = 0; ni < 4; ++ni)
        acc[mi][ni] = MFMA16(af[mi], bf[ni], acc[mi][ni]);
    __syncthreads();
  }
#pragma unroll
  for (int mi = 0; mi < 4; ++mi) {
    int row = m0 + wr + mi * 16 + g * 4;
#pragma unroll
    for (int ni = 0; ni < 4; ++ni) {
      int col = n0 + wc + ni * 16 + l15;
      float bv = b0[col];
#pragma unroll
      for (int i = 0; i < 4; ++i) {
        float v = acc[mi][ni][i] + bv;
        if (OUTF32)
          ((float*)Cout)[(size_t)(row + i) * ostride + col] = v;
        else
          ((u16*)Cout)[(size_t)(row + i) * ostride + col] = f2bf(v);
      }
    }
  }
}

// ------------- causal flash attention (r11 structure; redundant end-of-loop
// barrier REMOVED — top-of-iter __syncthreads already drains all waves' reads
// before any buffer is overwritten: scatter(t+1) targets Vt[(t+1)&1] (not the
// buffer compute(t) reads) and prefetch(t+2)'s Ks[t&1] write happens only
// after the NEXT top barrier, which drains compute(t)'s ds_reads) -----------
__global__ __launch_bounds__(256, 2) void attn_k(const u16* __restrict__ QKV,
                                                 u16* __restrict__ Yg) {
  __shared__ u16 Ks[2][64 * 64];
  __shared__ u16 Vt[2][64 * 64];

  const int tid = threadIdx.x;
  const int w = tid >> 6, lane = tid & 63;
  const int qi = lane & 31, h = lane >> 5;

  const int lid = blockIdx.x;
  const int a4 = lid >> 6;                 // 0..15
  const int gq = a4 >> 2, iq = a4 & 3;
  // perm = {15,13,11,9, 0,2,4,6, 14,12,10,8, 1,3,5,7}: heavy-first; stride-4
  // quadruples sum to 30 (balanced under round-robin placement)
  const int jt = gq == 0 ? 15 - 2 * iq : gq == 1 ? 2 * iq : gq == 2 ? 14 - 2 * iq : 1 + 2 * iq;
  const int bh = lid & 63;
  const int nt = 2 * jt + 2;

  const size_t baseQ = (size_t)(bh >> 4) * T_ * CR3 + (size_t)(bh & 15) * D_;
  const size_t baseY = (size_t)(bh >> 4) * T_ * C_ + (size_t)(bh & 15) * D_;
  const u16* Kg = QKV + baseQ + 1024;
  const u16* Vg = QKV + baseQ + 2048;

  const int srow = tid >> 3, schunk = tid & 7;
  const int sgcol = (schunk ^ (srow & 7)) * 8;
  const u16* Kgr = Kg + (size_t)srow * CR3 + sgcol;
  const u16* Vgr = Vg + (size_t)srow * CR3 + schunk * 8;

  const int qw0 = 128 * jt + 32 * w;
  const int q_abs = qw0 + qi;

  short8 qf0, qf1, qf2, qf3;
  {
    const u16* Qr = QKV + baseQ + (size_t)q_abs * CR3 + 8 * h;
    qf0 = *(const short8*)(Qr);      qf1 = *(const short8*)(Qr + 16);
    qf2 = *(const short8*)(Qr + 32); qf3 = *(const short8*)(Qr + 48);
  }

  ushort8_t va, vbr;
  gload16(Kgr, &Ks[0][tid * 8]);
  gload16(Kgr + (size_t)32 * CR3, &Ks[0][2048 + tid * 8]);
  va = *(const ushort8_t*)(Vgr);
  vbr = *(const ushort8_t*)(Vgr + (size_t)32 * CR3);

  f32x16 y0 = {}, y1 = {};
  float l_run = 0.f;
  const float M0 = 13.0f;   // fixed softmax exponent shift

  for (int t = 0; t < nt; ++t) {
    const int kv0 = t * 64;
    u16* Kb = Ks[t & 1];
    u16* Vb = Vt[t & 1];
    asm volatile("s_waitcnt vmcnt(0)" ::: "memory");
    {
      char* vbp = (char*)Vb;
#pragma unroll
      for (int j = 0; j < 8; ++j) {
        int d = schunk * 8 + j;
        int sl = ((schunk ^ j) & 7) << 4;
        *(u16*)(vbp + d * 128 + ((2 * srow) ^ sl)) = va[j];
        *(u16*)(vbp + d * 128 + ((2 * (srow + 32)) ^ sl)) = vbr[j];
      }
    }
    __syncthreads();
    if (t + 1 < nt) {
      int nkv = (t + 1) * 64;
      u16* dst = Ks[(t + 1) & 1];
      gload16(Kgr + (size_t)nkv * CR3, dst + tid * 8);
      gload16(Kgr + (size_t)(nkv + 32) * CR3, dst + 2048 + tid * 8);
      va = *(const ushort8_t*)(Vgr + (size_t)nkv * CR3);
      vbr = *(const ushort8_t*)(Vgr + (size_t)(nkv + 32) * CR3);
    }

    if (kv0 <= qw0 + 31) {
      f32x16 s0 = {}, s1 = {};
      {
        const int swq = (qi & 7) << 4;
        const char* kr0 = (const char*)Kb + qi * 128;
        const char* kr1 = (const char*)Kb + (qi + 32) * 128;
        short8 k0, k1;
        k0 = *(const short8*)(kr0 + ((16 * h) ^ swq));
        k1 = *(const short8*)(kr1 + ((16 * h) ^ swq));
        s0 = MFMA32(k0, qf0, s0); s1 = MFMA32(k1, qf0, s1);
        k0 = *(const short8*)(kr0 + ((32 + 16 * h) ^ swq));
        k1 = *(const short8*)(kr1 + ((32 + 16 * h) ^ swq));
        s0 = MFMA32(k0, qf1, s0); s1 = MFMA32(k1, qf1, s1);
        k0 = *(const short8*)(kr0 + ((64 + 16 * h) ^ swq));
        k1 = *(const short8*)(kr1 + ((64 + 16 * h) ^ swq));
        s0 = MFMA32(k0, qf2, s0); s1 = MFMA32(k1, qf2, s1);
        k0 = *(const short8*)(kr0 + ((96 + 16 * h) ^ swq));
        k1 = *(const short8*)(kr1 + ((96 + 16 * h) ^ swq));
        s0 = MFMA32(k0, qf3, s0); s1 = MFMA32(k1, qf3, s1);
      }
      if (kv0 + 63 > qw0) {
#pragma unroll
        for (int r = 0; r < 16; ++r) {
          int kvq = (r & 3) + 8 * (r >> 2) + 4 * h;
          if (kv0 + kvq > q_abs) s0[r] = -1e30f;
          if (kv0 + 32 + kvq > q_abs) s1[r] = -1e30f;
        }
      }
#pragma unroll
      for (int r = 0; r < 16; ++r) s0[r] = __builtin_amdgcn_exp2f(s0[r] - M0);
#pragma unroll
      for (int r = 0; r < 16; ++r) s1[r] = __builtin_amdgcn_exp2f(s1[r] - M0);
      {
        float a8[8];
#pragma unroll
        for (int r = 0; r < 8; ++r) a8[r] = (s0[r] + s0[r + 8]) + (s1[r] + s1[r + 8]);
#pragma unroll
        for (int r = 0; r < 4; ++r) a8[r] += a8[r + 4];
        l_run += (a8[0] + a8[1]) + (a8[2] + a8[3]);
      }
      unsigned pw[16];
      {
        unsigned a0, b0, a1, b1;
        a0 = cvtpk(s0[0], s0[1]);  b0 = cvtpk(s0[4], s0[5]);  pl32swap(a0, b0);
        a1 = cvtpk(s0[2], s0[3]);  b1 = cvtpk(s0[6], s0[7]);  pl32swap(a1, b1);
        pw[0] = a0; pw[1] = a1; pw[2] = b0; pw[3] = b1;
        a0 = cvtpk(s0[8], s0[9]);  b0 = cvtpk(s0[12], s0[13]); pl32swap(a0, b0);
        a1 = cvtpk(s0[10], s0[11]); b1 = cvtpk(s0[14], s0[15]); pl32swap(a1, b1);
        pw[4] = a0; pw[5] = a1; pw[6] = b0; pw[7] = b1;
        a0 = cvtpk(s1[0], s1[1]);  b0 = cvtpk(s1[4], s1[5]);  pl32swap(a0, b0);
        a1 = cvtpk(s1[2], s1[3]);  b1 = cvtpk(s1[6], s1[7]);  pl32swap(a1, b1);
        pw[8] = a0; pw[9] = a1; pw[10] = b0; pw[11] = b1;
        a0 = cvtpk(s1[8], s1[9]);  b0 = cvtpk(s1[12], s1[13]); pl32swap(a0, b0);
        a1 = cvtpk(s1[10], s1[11]); b1 = cvtpk(s1[14], s1[15]); pl32swap(a1, b1);
        pw[12] = a0; pw[13] = a1; pw[14] = b0; pw[15] = b1;
      }
      {
        const char* vb0 = (const char*)Vb + qi * 128;
        const char* vb1 = (const char*)Vb + (qi + 32) * 128;
        const int sx0 = (((qi >> 3) ^ qi) & 7) << 4;
        const int sx1 = sx0 ^ 0x40;
#pragma unroll
        for (int c = 0; c < 4; ++c) {
          int cb = 32 * c + 16 * h;
          uint4_t pt = {pw[c * 4 + 0], pw[c * 4 + 1], pw[c * 4 + 2], pw[c * 4 + 3]};
          short8 pa = __builtin_bit_cast(short8, pt);
          short8 v0 = *(const short8*)(vb0 + (cb ^ sx0));
          short8 v1 = *(const short8*)(vb1 + (cb ^ sx1));
          y0 = MFMA32(pa, v0, y0);
          y1 = MFMA32(pa, v1, y1);
        }
      }
    }
    // (end-of-loop __syncthreads removed — see header comment hazard audit)
  }

  l_run += __shfl_xor(l_run, 32);
  float linv = 1.0f / l_run;
#pragma unroll
  for (int r = 0; r < 16; ++r) {
    int qp = (r & 3) + 8 * (r >> 2) + 4 * h;
    float lv = __shfl(linv, qp);
    size_t row = baseY + (size_t)(qw0 + qp) * C_;
    Yg[row + qi] = f2bf(y0[r] * lv);
    Yg[row + 32 + qi] = f2bf(y1[r] * lv);
  }
}

extern "C" void kernel_launch(void* const* d_in, const int* in_sizes, int n_in,
                              void* d_out, int out_size, void* d_ws, size_t ws_size,
                              hipStream_t stream) {
  const float* x  = (const float*)d_in[0];
  const float* Wq = (const float*)d_in[1];
  const float* bq = (const float*)d_in[2];
  const float* Wk = (const float*)d_in[3];
  const float* bk = (const float*)d_in[4];
  const float* Wv = (const float*)d_in[5];
  const float* bv = (const float*)d_in[6];
  const float* Wo = (const float*)d_in[7];
  const float* bo = (const float*)d_in[8];
  float* out = (float*)d_out;

  char* ws = (char*)d_ws;
  u16* xb   = (u16*)ws;                           // 16 MiB (reused as Yb)
  u16* WT   = (u16*)(ws + (size_t)16777216);      // 4 x 2 MiB
  u16* QKVb = (u16*)(ws + (size_t)25165824);      // 48 MiB
  u16* Yb = xb;

  convx_k<<<dim3(M_ * C_ / 1024), 256, 0, stream>>>(x, xb);
  wconv_k<<<dim3(16, 16, 4), 256, 0, stream>>>(Wq, Wk, Wv, Wo, WT);
  // fused QKV projection: 128x256 ring kernel, 4 waves, grid 768
  gemm8_k<<<dim3(768), 256, 0, stream>>>(xb, WT, bq, bk, bv, 0.125f * 1.44269504f, QKVb);
  attn_k<<<dim3(1024), 256, 0, stream>>>(QKVb, Yb);
  gemm_k<1><<<dim3(64, 8), 256, 0, stream>>>(Yb, C_, WT + (size_t)3 * 1048576, bo, out, C_);
}

// Round 15
// 163.227 us; speedup vs baseline: 1.4246x; 1.0026x over previous
//
#include <hip/hip_runtime.h>

#define B_ 4
#define T_ 2048
#define C_ 1024
#define H_ 16
#define D_ 64
#define M_ (B_*T_)   // 8192 rows
#define CR3 3072     // fused QKV row stride

typedef unsigned short u16;
typedef __attribute__((ext_vector_type(8))) short short8;
typedef __attribute__((ext_vector_type(8))) unsigned short ushort8_t;
typedef __attribute__((ext_vector_type(4))) unsigned short ushort4_t;
typedef __attribute__((ext_vector_type(4))) float floatx4;
typedef __attribute__((ext_vector_type(16))) float f32x16;
typedef __attribute__((ext_vector_type(4))) unsigned int uint4_t;

__device__ __forceinline__ u16 f2bf(float f) {
  union { float f; unsigned u; } v; v.f = f;
  unsigned r = v.u + 0x7fffu + ((v.u >> 16) & 1u);
  return (u16)(r >> 16);
}

__device__ __forceinline__ void gload16(const void* g, void* l) {
  __builtin_amdgcn_global_load_lds((__attribute__((address_space(1))) void*)(g),
                                   (__attribute__((address_space(3))) void*)(l),
                                   16, 0, 0);
}

__device__ __forceinline__ unsigned cvtpk(float lo, float hi) {
  unsigned r;
  asm("v_cvt_pk_bf16_f32 %0, %1, %2" : "=v"(r) : "v"(lo), "v"(hi));
  return r;
}

__device__ __forceinline__ void pl32swap(unsigned &a, unsigned &b) {
  asm volatile("v_permlane32_swap_b32 %0, %1" : "+v"(a), "+v"(b));
}

#define MFMA32(a, b, c) __builtin_amdgcn_mfma_f32_32x32x16_bf16(a, b, c, 0, 0, 0)
#define MFMA16(a, b, c) __builtin_amdgcn_mfma_f32_16x16x32_bf16(a, b, c, 0, 0, 0)

// ---------------- x -> bf16 ----------------
__global__ __launch_bounds__(256) void convx_k(const float* __restrict__ x,
                                               u16* __restrict__ o) {
  int i = (blockIdx.x * 256 + threadIdx.x) * 4;
  floatx4 v = *(const floatx4*)(x + i);
  ushort4_t r;
#pragma unroll
  for (int j = 0; j < 4; ++j) r[j] = f2bf(v[j]);
  *(ushort4_t*)(o + i) = r;
}

// ------------- W (K x N) -> WT (N x K) bf16 (Wq pre-scaled), LDS transpose ----
__global__ __launch_bounds__(256) void wconv_k(const float* __restrict__ W0,
                                               const float* __restrict__ W1,
                                               const float* __restrict__ W2,
                                               const float* __restrict__ W3,
                                               u16* __restrict__ WT) {
  __shared__ float tile[64][65];
  const float* W = blockIdx.z == 0 ? W0 : blockIdx.z == 1 ? W1 : blockIdx.z == 2 ? W2 : W3;
  const float sc = blockIdx.z == 0 ? 0.125f * 1.44269504f : 1.0f;  // 1/sqrt(D)*log2e into Wq
  u16* Wt = WT + (size_t)blockIdx.z * (C_ * C_);
  int k0 = blockIdx.x * 64, n0 = blockIdx.y * 64;
  int t = threadIdx.x;
  int r = t >> 2, c0 = (t & 3) * 16;
#pragma unroll
  for (int j = 0; j < 4; ++j) {
    floatx4 v = *(const floatx4*)(W + (size_t)(k0 + r) * C_ + n0 + c0 + j * 4);
#pragma unroll
    for (int jj = 0; jj < 4; ++jj) tile[r][c0 + j * 4 + jj] = v[jj];
  }
  __syncthreads();
  ushort8_t o0, o1;
#pragma unroll
  for (int j = 0; j < 8; ++j) o0[j] = f2bf(tile[c0 + j][r] * sc);
#pragma unroll
  for (int j = 0; j < 8; ++j) o1[j] = f2bf(tile[c0 + 8 + j][r] * sc);
  *(ushort8_t*)(Wt + (size_t)(n0 + r) * C_ + k0 + c0) = o0;
  *(ushort8_t*)(Wt + (size_t)(n0 + r) * C_ + k0 + c0 + 8) = o1;
}

// ---- 256x256 8-phase GEMM for QKV (m201-structure port) --------------------
// 8 waves (2M x 4N), per-wave 128x64 out. BK=64, 16 K-tiles, dbuf LDS 128KiB
// (A 256x64 | B 256x64 per buf, XOR-swizzled chunk^(row&7), both sides).
// Per phase: {ds_read 4-8 b128; stage 2 quarter-units (gload16); [vmcnt(4) at
// ph4/ph8]; s_barrier; lgkmcnt(0)+sched_barrier; setprio(1); 16 MFMA;
// setprio(0); s_barrier}. Stage plan (iter i computes tiles 2i,2i+1):
//  ph1: AQ01(2i+1)->d1  ph2: AQ23(2i+1)->d1  ph3: BQ01(2i+2)->d0
//  ph4: BQ23(2i+2)->d0  ph5: AQ01(2i+2)->d0  ph6: AQ23(2i+2)->d0
//  ph7: BQ01(2i+3)->d1  ph8: BQ23(2i+3)->d1
// Last-read audit (64-row quarters): every stage target's last reader >=1
// barrier before issue; vmcnt(4) at ph4 covers ph5-8 reads, at ph8 covers
// next-iter ph1-4 reads. Tail (i=7): ph3-8 stages off, ph4 vmcnt(0).
__global__ __launch_bounds__(512, 2) void gemm8_k(const u16* __restrict__ A,
                                                  const u16* __restrict__ Wt,
                                                  const float* __restrict__ b0,
                                                  const float* __restrict__ b1,
                                                  const float* __restrict__ b2,
                                                  float bsc0,
                                                  u16* __restrict__ Cout) {
  __shared__ u16 lds[65536];   // 2 dbuf x (A 16384 | B 16384) u16
  const int tid = threadIdx.x;
  const int lane = tid & 63, w = tid >> 6;
  const int wm = w >> 2, wn = w & 3;
  const int l15 = lane & 15, g = lane >> 4;

  const int bid = blockIdx.x;                 // 384 = 8 XCD chunks of 48
  const int swz = (bid & 7) * 48 + (bid >> 3);
  const int bn = swz >> 5, bm = swz & 31;     // 32 M-tiles x 12 N-tiles
  const int m0 = bm * 256, n0 = bn * 256;

  // staging: thread t covers chunk t of each 64-row quarter-unit (1 gload ea)
  const int srow = tid >> 3;                  // 0..63 (row within quarter)
  const int scol = ((tid & 7) ^ (srow & 7)) * 8;   // pre-swizzled source col
  const u16* gAsrc = A  + (size_t)(m0 + srow) * 1024 + scol;
  const u16* gBsrc = Wt + (size_t)(n0 + srow) * 1024 + scol;

#define SQA(DD, Q, KT) gload16(gAsrc + (size_t)(Q) * 65536 + (size_t)(KT) * 64, \
                               lds + (DD) * 32768 + (Q) * 4096 + tid * 8)
#define SQB(DD, Q, KT) gload16(gBsrc + (size_t)(Q) * 65536 + (size_t)(KT) * 64, \
                               lds + (DD) * 32768 + 16384 + (Q) * 4096 + tid * 8)

  floatx4 acc[8][4] = {};
  short8 bk0[4], bk1[4];      // B frags held per ks (static names)

#define PHASE(DD, MH, KS, READB, BKREG, STG, VM) do {                       \
    short8 af_[4];                                                          \
    _Pragma("unroll") for (int mi = 0; mi < 4; ++mi) {                      \
      int ar_ = wm * 128 + (MH) * 64 + mi * 16 + l15;                       \
      af_[mi] = *(const short8*)(lds + (DD) * 32768 + ar_ * 64 +            \
                                 ((((KS) * 4 + g) ^ (ar_ & 7)) << 3));      \
    }                                                                       \
    if (READB) {                                                            \
      _Pragma("unroll") for (int ni = 0; ni < 4; ++ni) {                    \
        int br_ = wn * 64 + ni * 16 + l15;                                  \
        BKREG[ni] = *(const short8*)(lds + (DD) * 32768 + 16384 + br_ * 64 +\
                                     ((((KS) * 4 + g) ^ (br_ & 7)) << 3));  \
      }                                                                     \
    }                                                                       \
    STG;                                                                    \
    VM;                                                                     \
    __builtin_amdgcn_s_barrier();                                           \
    asm volatile("s_waitcnt lgkmcnt(0)" ::: "memory");                      \
    __builtin_amdgcn_sched_barrier(0);                                      \
    __builtin_amdgcn_s_setprio(1);                                          \
    _Pragma("unroll") for (int mi = 0; mi < 4; ++mi)                        \
      _Pragma("unroll") for (int ni = 0; ni < 4; ++ni)                      \
        acc[(MH) * 4 + mi][ni] = MFMA16(af_[mi], BKREG[ni],                 \
                                        acc[(MH) * 4 + mi][ni]);            \
    __builtin_amdgcn_s_setprio(0);                                          \
    __builtin_amdgcn_sched_barrier(0);                                      \
    __builtin_amdgcn_s_barrier();                                           \
  } while (0)

#define VM4 asm volatile("s_waitcnt vmcnt(4)" ::: "memory")
#define VM0 asm volatile("s_waitcnt vmcnt(0)" ::: "memory")
#define NOP ((void)0)

  // prologue: tile0 full (A Q0-3, B Q0-3) -> d0; B Q0-3 of tile1 -> d1
  SQA(0, 0, 0); SQA(0, 1, 0); SQA(0, 2, 0); SQA(0, 3, 0);
  SQB(0, 0, 0); SQB(0, 1, 0); SQB(0, 2, 0); SQB(0, 3, 0);
  SQB(1, 0, 1); SQB(1, 1, 1); SQB(1, 2, 1); SQB(1, 3, 1);
  VM4;
  __builtin_amdgcn_s_barrier();

  for (int i = 0; i < 8; ++i) {
    const int t1 = 2 * i + 1, T2 = 2 * i + 2, T3 = 2 * i + 3;
    const bool st = (i < 7);
    // tile 2i from d0
    PHASE(0, 0, 0, 1, bk0, { SQA(1, 0, t1); SQA(1, 1, t1); }, NOP);
    PHASE(0, 0, 1, 1, bk1, { SQA(1, 2, t1); SQA(1, 3, t1); }, NOP);
    PHASE(0, 1, 0, 0, bk0, { if (st) { SQB(0, 0, T2); SQB(0, 1, T2); } }, NOP);
    if (st) { PHASE(0, 1, 1, 0, bk1, { SQB(0, 2, T2); SQB(0, 3, T2); }, VM4); }
    else    { PHASE(0, 1, 1, 0, bk1, NOP, VM0); }
    // tile 2i+1 from d1
    PHASE(1, 0, 0, 1, bk0, { if (st) { SQA(0, 0, T2); SQA(0, 1, T2); } }, NOP);
    PHASE(1, 0, 1, 1, bk1, { if (st) { SQA(0, 2, T2); SQA(0, 3, T2); } }, NOP);
    PHASE(1, 1, 0, 0, bk0, { if (st) { SQB(1, 0, T3); SQB(1, 1, T3); } }, NOP);
    if (st) { PHASE(1, 1, 1, 0, bk1, { SQB(1, 2, T3); SQB(1, 3, T3); }, VM4); }
    else    { PHASE(1, 1, 1, 0, bk1, NOP, VM0); }
  }

  // epilogue: bias (col-segment select) + bf16 store at stride CR3
#pragma unroll
  for (int mi8 = 0; mi8 < 8; ++mi8) {
    int row = m0 + wm * 128 + mi8 * 16 + g * 4;
#pragma unroll
    for (int ni = 0; ni < 4; ++ni) {
      int col = n0 + wn * 64 + ni * 16 + l15;
      int seg = col >> 10;
      const float* bp = seg == 0 ? b0 : seg == 1 ? b1 : b2;
      float bv = bp[col & 1023] * (seg == 0 ? bsc0 : 1.0f);
#pragma unroll
      for (int i = 0; i < 4; ++i)
        Cout[(size_t)(row + i) * CR3 + col] = f2bf(acc[mi8][ni][i] + bv);
    }
  }
}

// ---- GEMM: C[M,N] = A[M,astride]@WT[N,1024]^T + bias, 128x128 (out proj) ---
template <int OUTF32>
__global__ __launch_bounds__(256, 2) void gemm_k(const u16* __restrict__ A,
                                                 int astride,
                                                 const u16* __restrict__ Wt,
                                                 const float* __restrict__ b0,
                                                 void* __restrict__ Cout, int ostride) {
  __shared__ u16 As[128 * 32];
  __shared__ u16 Bs[128 * 32];
  const int tid = threadIdx.x;
  const int w = tid >> 6, lane = tid & 63;
  const int wr = (w >> 1) * 64, wc = (w & 1) * 64;
  const int l15 = lane & 15, g = lane >> 4;
  const int m0 = blockIdx.x * 128, n0 = blockIdx.y * 128;

  floatx4 acc[4][4] = {};

  const int srow = tid >> 2;
  const int scol = ((tid & 3) ^ ((srow >> 1) & 3)) * 8;
  const u16* ga = A + (size_t)(m0 + srow) * astride + scol;
  const u16* gb = Wt + (size_t)(n0 + srow) * C_ + scol;
  u16* lA = As + tid * 8;
  u16* lB = Bs + tid * 8;

  for (int kt = 0; kt < C_; kt += 32) {
    gload16(ga + kt, lA);
    gload16(ga + kt + (size_t)64 * astride, lA + 64 * 32);
    gload16(gb + kt, lB);
    gload16(gb + kt + (size_t)64 * C_, lB + 64 * 32);
    asm volatile("s_waitcnt vmcnt(0)" ::: "memory");
    __syncthreads();
    short8 af[4], bf[4];
#pragma unroll
    for (int i = 0; i < 4; ++i) {
      int ra = wr + i * 16 + l15;
      af[i] = *(const short8*)(As + ra * 32 + ((g ^ ((ra >> 1) & 3)) << 3));
    }
#pragma unroll
    for (int i = 0; i < 4; ++i) {
      int rb = wc + i * 16 + l15;
      bf[i] = *(const short8*)(Bs + rb * 32 + ((g ^ ((rb >> 1) & 3)) << 3));
    }
#pragma unroll
    for (int mi = 0; mi < 4; ++mi)
#pragma unroll
      for (int ni = 0; ni < 4; ++ni)
        acc[mi][ni] = MFMA16(af[mi], bf[ni], acc[mi][ni]);
    __syncthreads();
  }
#pragma unroll
  for (int mi = 0; mi < 4; ++mi) {
    int row = m0 + wr + mi * 16 + g * 4;
#pragma unroll
    for (int ni = 0; ni < 4; ++ni) {
      int col = n0 + wc + ni * 16 + l15;
      float bv = b0[col];
#pragma unroll
      for (int i = 0; i < 4; ++i) {
        float v = acc[mi][ni][i] + bv;
        if (OUTF32)
          ((float*)Cout)[(size_t)(row + i) * ostride + col] = v;
        else
          ((u16*)Cout)[(size_t)(row + i) * ostride + col] = f2bf(v);
      }
    }
  }
}

// ------------- causal flash attention (r14 structure + T5 setprio) ----------
__global__ __launch_bounds__(256, 2) void attn_k(const u16* __restrict__ QKV,
                                                 u16* __restrict__ Yg) {
  __shared__ u16 Ks[2][64 * 64];
  __shared__ u16 Vt[2][64 * 64];

  const int tid = threadIdx.x;
  const int w = tid >> 6, lane = tid & 63;
  const int qi = lane & 31, h = lane >> 5;

  const int lid = blockIdx.x;
  const int a4 = lid >> 6;                 // 0..15
  const int gq = a4 >> 2, iq = a4 & 3;
  const int jt = gq == 0 ? 15 - 2 * iq : gq == 1 ? 2 * iq : gq == 2 ? 14 - 2 * iq : 1 + 2 * iq;
  const int bh = lid & 63;
  const int nt = 2 * jt + 2;

  const size_t baseQ = (size_t)(bh >> 4) * T_ * CR3 + (size_t)(bh & 15) * D_;
  const size_t baseY = (size_t)(bh >> 4) * T_ * C_ + (size_t)(bh & 15) * D_;
  const u16* Kg = QKV + baseQ + 1024;
  const u16* Vg = QKV + baseQ + 2048;

  const int srow = tid >> 3, schunk = tid & 7;
  const int sgcol = (schunk ^ (srow & 7)) * 8;
  const u16* Kgr = Kg + (size_t)srow * CR3 + sgcol;
  const u16* Vgr = Vg + (size_t)srow * CR3 + schunk * 8;

  const int qw0 = 128 * jt + 32 * w;
  const int q_abs = qw0 + qi;

  short8 qf0, qf1, qf2, qf3;
  {
    const u16* Qr = QKV + baseQ + (size_t)q_abs * CR3 + 8 * h;
    qf0 = *(const short8*)(Qr);      qf1 = *(const short8*)(Qr + 16);
    qf2 = *(const short8*)(Qr + 32); qf3 = *(const short8*)(Qr + 48);
  }

  ushort8_t va, vbr;
  gload16(Kgr, &Ks[0][tid * 8]);
  gload16(Kgr + (size_t)32 * CR3, &Ks[0][2048 + tid * 8]);
  va = *(const ushort8_t*)(Vgr);
  vbr = *(const ushort8_t*)(Vgr + (size_t)32 * CR3);

  f32x16 y0 = {}, y1 = {};
  float l_run = 0.f;
  const float M0 = 13.0f;   // fixed softmax exponent shift

  for (int t = 0; t < nt; ++t) {
    const int kv0 = t * 64;
    u16* Kb = Ks[t & 1];
    u16* Vb = Vt[t & 1];
    asm volatile("s_waitcnt vmcnt(0)" ::: "memory");
    {
      char* vbp = (char*)Vb;
#pragma unroll
      for (int j = 0; j < 8; ++j) {
        int d = schunk * 8 + j;
        int sl = ((schunk ^ j) & 7) << 4;
        *(u16*)(vbp + d * 128 + ((2 * srow) ^ sl)) = va[j];
        *(u16*)(vbp + d * 128 + ((2 * (srow + 32)) ^ sl)) = vbr[j];
      }
    }
    __syncthreads();
    if (t + 1 < nt) {
      int nkv = (t + 1) * 64;
      u16* dst = Ks[(t + 1) & 1];
      gload16(Kgr + (size_t)nkv * CR3, dst + tid * 8);
      gload16(Kgr + (size_t)(nkv + 32) * CR3, dst + 2048 + tid * 8);
      va = *(const ushort8_t*)(Vgr + (size_t)nkv * CR3);
      vbr = *(const ushort8_t*)(Vgr + (size_t)(nkv + 32) * CR3);
    }

    if (kv0 <= qw0 + 31) {
      f32x16 s0 = {}, s1 = {};
      {
        const int swq = (qi & 7) << 4;
        const char* kr0 = (const char*)Kb + qi * 128;
        const char* kr1 = (const char*)Kb + (qi + 32) * 128;
        short8 k0, k1;
        k0 = *(const short8*)(kr0 + ((16 * h) ^ swq));
        k1 = *(const short8*)(kr1 + ((16 * h) ^ swq));
        __builtin_amdgcn_s_setprio(1);
        s0 = MFMA32(k0, qf0, s0); s1 = MFMA32(k1, qf0, s1);
        __builtin_amdgcn_s_setprio(0);
        k0 = *(const short8*)(kr0 + ((32 + 16 * h) ^ swq));
        k1 = *(const short8*)(kr1 + ((32 + 16 * h) ^ swq));
        __builtin_amdgcn_s_setprio(1);
        s0 = MFMA32(k0, qf1, s0); s1 = MFMA32(k1, qf1, s1);
        __builtin_amdgcn_s_setprio(0);
        k0 = *(const short8*)(kr0 + ((64 + 16 * h) ^ swq));
        k1 = *(const short8*)(kr1 + ((64 + 16 * h) ^ swq));
        __builtin_amdgcn_s_setprio(1);
        s0 = MFMA32(k0, qf2, s0); s1 = MFMA32(k1, qf2, s1);
        __builtin_amdgcn_s_setprio(0);
        k0 = *(const short8*)(kr0 + ((96 + 16 * h) ^ swq));
        k1 = *(const short8*)(kr1 + ((96 + 16 * h) ^ swq));
        __builtin_amdgcn_s_setprio(1);
        s0 = MFMA32(k0, qf3, s0); s1 = MFMA32(k1, qf3, s1);
        __builtin_amdgcn_s_setprio(0);
      }
      if (kv0 + 63 > qw0) {
#pragma unroll
        for (int r = 0; r < 16; ++r) {
          int kvq = (r & 3) + 8 * (r >> 2) + 4 * h;
          if (kv0 + kvq > q_abs) s0[r] = -1e30f;
          if (kv0 + 32 + kvq > q_abs) s1[r] = -1e30f;
        }
      }
#pragma unroll
      for (int r = 0; r < 16; ++r) s0[r] = __builtin_amdgcn_exp2f(s0[r] - M0);
#pragma unroll
      for (int r = 0; r < 16; ++r) s1[r] = __builtin_amdgcn_exp2f(s1[r] - M0);
      {
        float a8[8];
#pragma unroll
        for (int r = 0; r < 8; ++r) a8[r] = (s0[r] + s0[r + 8]) + (s1[r] + s1[r + 8]);
#pragma unroll
        for (int r = 0; r < 4; ++r) a8[r] += a8[r + 4];
        l_run += (a8[0] + a8[1]) + (a8[2] + a8[3]);
      }
      unsigned pw[16];
      {
        unsigned a0, b0, a1, b1;
        a0 = cvtpk(s0[0], s0[1]);  b0 = cvtpk(s0[4], s0[5]);  pl32swap(a0, b0);
        a1 = cvtpk(s0[2], s0[3]);  b1 = cvtpk(s0[6], s0[7]);  pl32swap(a1, b1);
        pw[0] = a0; pw[1] = a1; pw[2] = b0; pw[3] = b1;
        a0 = cvtpk(s0[8], s0[9]);  b0 = cvtpk(s0[12], s0[13]); pl32swap(a0, b0);
        a1 = cvtpk(s0[10], s0[11]); b1 = cvtpk(s0[14], s0[15]); pl32swap(a1, b1);
        pw[4] = a0; pw[5] = a1; pw[6] = b0; pw[7] = b1;
        a0 = cvtpk(s1[0], s1[1]);  b0 = cvtpk(s1[4], s1[5]);  pl32swap(a0, b0);
        a1 = cvtpk(s1[2], s1[3]);  b1 = cvtpk(s1[6], s1[7]);  pl32swap(a1, b1);
        pw[8] = a0; pw[9] = a1; pw[10] = b0; pw[11] = b1;
        a0 = cvtpk(s1[8], s1[9]);  b0 = cvtpk(s1[12], s1[13]); pl32swap(a0, b0);
        a1 = cvtpk(s1[10], s1[11]); b1 = cvtpk(s1[14], s1[15]); pl32swap(a1, b1);
        pw[12] = a0; pw[13] = a1; pw[14] = b0; pw[15] = b1;
      }
      {
        const char* vb0 = (const char*)Vb + qi * 128;
        const char* vb1 = (const char*)Vb + (qi + 32) * 128;
        const int sx0 = (((qi >> 3) ^ qi) & 7) << 4;
        const int sx1 = sx0 ^ 0x40;
#pragma unroll
        for (int c = 0; c < 4; ++c) {
          int cb = 32 * c + 16 * h;
          uint4_t pt = {pw[c * 4 + 0], pw[c * 4 + 1], pw[c * 4 + 2], pw[c * 4 + 3]};
          short8 pa = __builtin_bit_cast(short8, pt);
          short8 v0 = *(const short8*)(vb0 + (cb ^ sx0));
          short8 v1 = *(const short8*)(vb1 + (cb ^ sx1));
          __builtin_amdgcn_s_setprio(1);
          y0 = MFMA32(pa, v0, y0);
          y1 = MFMA32(pa, v1, y1);
          __builtin_amdgcn_s_setprio(0);
        }
      }
    }
  }

  l_run += __shfl_xor(l_run, 32);
  float linv = 1.0f / l_run;
#pragma unroll
  for (int r = 0; r < 16; ++r) {
    int qp = (r & 3) + 8 * (r >> 2) + 4 * h;
    float lv = __shfl(linv, qp);
    size_t row = baseY + (size_t)(qw0 + qp) * C_;
    Yg[row + qi] = f2bf(y0[r] * lv);
    Yg[row + 32 + qi] = f2bf(y1[r] * lv);
  }
}

extern "C" void kernel_launch(void* const* d_in, const int* in_sizes, int n_in,
                              void* d_out, int out_size, void* d_ws, size_t ws_size,
                              hipStream_t stream) {
  const float* x  = (const float*)d_in[0];
  const float* Wq = (const float*)d_in[1];
  const float* bq = (const float*)d_in[2];
  const float* Wk = (const float*)d_in[3];
  const float* bk = (const float*)d_in[4];
  const float* Wv = (const float*)d_in[5];
  const float* bv = (const float*)d_in[6];
  const float* Wo = (const float*)d_in[7];
  const float* bo = (const float*)d_in[8];
  float* out = (float*)d_out;

  char* ws = (char*)d_ws;
  u16* xb   = (u16*)ws;                           // 16 MiB (reused as Yb)
  u16* WT   = (u16*)(ws + (size_t)16777216);      // 4 x 2 MiB
  u16* QKVb = (u16*)(ws + (size_t)25165824);      // 48 MiB
  u16* Yb = xb;

  convx_k<<<dim3(M_ * C_ / 1024), 256, 0, stream>>>(x, xb);
  wconv_k<<<dim3(16, 16, 4), 256, 0, stream>>>(Wq, Wk, Wv, Wo, WT);
  // fused QKV projection: 256x256 8-phase kernel, grid 384 (8x48 XCD)
  gemm8_k<<<dim3(384), 512, 0, stream>>>(xb, WT, bq, bk, bv, 0.125f * 1.44269504f, QKVb);
  attn_k<<<dim3(1024), 256, 0, stream>>>(QKVb, Yb);
  gemm_k<1><<<dim3(64, 8), 256, 0, stream>>>(Yb, C_, WT + (size_t)3 * 1048576, bo, out, C_);
}